// Round 4
// baseline (199.169 us; speedup 1.0000x reference)
//
#include <hip/hip_runtime.h>
#include <hip/hip_fp16.h>
#include <hip/hip_cooperative_groups.h>
#include <math.h>

// ---------------------------------------------------------------------------
// HematoxylinFFTModel round 4: cooperative fusion of colfft+coeff+norm.
//  - rowfft unchanged (radix-4 wave-sync, Hermitian row-pair packing).
//  - k_colnorm: 512 blocks (64 img x 8 col-groups), each owns 32 columns
//    (4 passes of 8; group 0 does a 5th pass for u=256). lv kept in LDS as
//    fp16 across grid.sync(); after sync every block folds its image's 8
//    partials into (A,B) and writes final out directly (direct + mirror).
//    Eliminates the 128 MB logmag write+read round-trip and 2 launches.
// ---------------------------------------------------------------------------

#define PI_F 3.14159265358979323846f
#define SW(i) ((i) + ((i) >> 4))
#define FSTR 544            // rowfft per-FFT LDS stride in float2
#define CSTR 548            // colfft per-column stride (bank offset 8/col)
#define LVSTR 520           // lvh per-column stride in halves (bank-spread)

namespace cg = cooperative_groups;

// digit reversal for stage order [2,4,4,4,4]
__device__ __forceinline__ int drev9(int n) {
    return ((n & 3) << 7) | (((n >> 2) & 3) << 5) | (((n >> 4) & 3) << 3)
         | (((n >> 6) & 3) << 1) | (n >> 8);
}

__device__ __forceinline__ float2 cmul(float2 a, float2 w) {
    return make_float2(a.x * w.x - a.y * w.y, a.x * w.y + a.y * w.x);
}

__device__ __forceinline__ void r2bf(float2* Xc, int m) {
    float2 a = Xc[SW(2 * m)], b = Xc[SW(2 * m + 1)];
    Xc[SW(2 * m)]     = make_float2(a.x + b.x, a.y + b.y);
    Xc[SW(2 * m + 1)] = make_float2(a.x - b.x, a.y - b.y);
}

__device__ __forceinline__ void r4bf(float2* Xc, const float2* TW, int j, int log2L) {
    const int L = 1 << log2L;
    const int kk = j & (L - 1);
    const int base = ((j >> log2L) << (log2L + 2)) + kk;
    const int t1 = kk << (7 - log2L);
    float2 a0 = Xc[SW(base)];
    float2 a1 = cmul(Xc[SW(base + L)],     TW[t1]);
    float2 a2 = cmul(Xc[SW(base + 2 * L)], TW[2 * t1]);
    float2 a3 = cmul(Xc[SW(base + 3 * L)], TW[3 * t1]);
    float2 t0 = make_float2(a0.x + a2.x, a0.y + a2.y);
    float2 u0 = make_float2(a0.x - a2.x, a0.y - a2.y);
    float2 t2 = make_float2(a1.x + a3.x, a1.y + a3.y);
    float2 u1 = make_float2(a1.x - a3.x, a1.y - a3.y);
    Xc[SW(base)]         = make_float2(t0.x + t2.x, t0.y + t2.y);
    Xc[SW(base + 2 * L)] = make_float2(t0.x - t2.x, t0.y - t2.y);
    Xc[SW(base + L)]     = make_float2(u0.x + u1.y, u0.y - u1.x);
    Xc[SW(base + 3 * L)] = make_float2(u0.x - u1.y, u0.y + u1.x);
}

__device__ __forceinline__ void hstore(float2* Xw, int c,
                                       float r0v, float g0v, float b0v,
                                       float r1v, float g1v, float b1v,
                                       float w0, float w1, float w2) {
    r0v = fminf(fmaxf(r0v, 1e-6f), 1.0f);
    g0v = fminf(fmaxf(g0v, 1e-6f), 1.0f);
    b0v = fminf(fmaxf(b0v, 1e-6f), 1.0f);
    r1v = fminf(fmaxf(r1v, 1e-6f), 1.0f);
    g1v = fminf(fmaxf(g1v, 1e-6f), 1.0f);
    b1v = fminf(fmaxf(b1v, 1e-6f), 1.0f);
    float h0 = fmaxf(w0 * __log2f(r0v) + w1 * __log2f(g0v) + w2 * __log2f(b0v), 0.0f);
    float h1 = fmaxf(w0 * __log2f(r1v) + w1 * __log2f(g1v) + w2 * __log2f(b1v), 0.0f);
    Xw[SW(drev9(c))] = make_float2(h0, h1);
}

// Pass 1: hematoxylin + packed row-pair FFT, 4 FFTs (8 rows) per block.
__global__ __launch_bounds__(256) void k_rowfft(const float* __restrict__ x,
                                                float2* __restrict__ F,
                                                float w0, float w1, float w2) {
    const int b = blockIdx.x >> 6;
    const int p = blockIdx.x & 63;
    __shared__ float2 X[4 * FSTR];
    __shared__ float2 TW[512];
    const int tid = threadIdx.x;
    {
        float sn, cs;
        __sincosf(-PI_F * (float)tid * (1.0f / 256.0f), &sn, &cs);
        TW[tid]       = make_float2(cs, sn);
        TW[tid + 256] = make_float2(-cs, -sn);
    }
    const int w = tid >> 6, lane = tid & 63;
    float2* Xw = X + w * FSTR;
    const float* xb = x + (size_t)b * 786432;
    const int r0 = (p << 3) + (w << 1);

    #pragma unroll
    for (int q = 0; q < 2; ++q) {
        const int cb = (q << 8) + (lane << 2);
        float4 R0 = *(const float4*)(xb +          (r0 << 9) + cb);
        float4 G0 = *(const float4*)(xb + 262144 + (r0 << 9) + cb);
        float4 B0 = *(const float4*)(xb + 524288 + (r0 << 9) + cb);
        float4 R1 = *(const float4*)(xb +          ((r0 + 1) << 9) + cb);
        float4 G1 = *(const float4*)(xb + 262144 + ((r0 + 1) << 9) + cb);
        float4 B1 = *(const float4*)(xb + 524288 + ((r0 + 1) << 9) + cb);
        hstore(Xw, cb + 0, R0.x, G0.x, B0.x, R1.x, G1.x, B1.x, w0, w1, w2);
        hstore(Xw, cb + 1, R0.y, G0.y, B0.y, R1.y, G1.y, B1.y, w0, w1, w2);
        hstore(Xw, cb + 2, R0.z, G0.z, B0.z, R1.z, G1.z, B1.z, w0, w1, w2);
        hstore(Xw, cb + 3, R0.w, G0.w, B0.w, R1.w, G1.w, B1.w, w0, w1, w2);
    }
    __syncthreads();

    #pragma unroll
    for (int t = 0; t < 4; ++t) r2bf(Xw, lane + (t << 6));
    __builtin_amdgcn_wave_barrier();
    #pragma unroll
    for (int lg = 1; lg <= 7; lg += 2) {
        r4bf(Xw, TW, lane, lg);
        r4bf(Xw, TW, lane + 64, lg);
        __builtin_amdgcn_wave_barrier();
    }

    float2* Fb = F + ((size_t)b << 18);
    #pragma unroll
    for (int t = 0; t < 4; ++t) {
        int k = lane + (t << 6);
        int m = (512 - k) & 511;
        float2 zk = Xw[SW(k)];
        float2 zm = Xw[SW(m)];
        Fb[(r0 << 9) + k]       = make_float2(0.5f * (zk.x + zm.x),  0.5f * (zk.y - zm.y));
        Fb[((r0 + 1) << 9) + k] = make_float2(0.5f * (zk.y + zm.y), -0.5f * (zk.x - zm.x));
    }
    if (lane == 0) {
        float2 z = Xw[SW(256)];
        Fb[(r0 << 9) + 256]       = make_float2(z.x, 0.0f);
        Fb[((r0 + 1) << 9) + 256] = make_float2(z.y, 0.0f);
    }
}

// Pass 2 (cooperative): column FFTs + stats + grid.sync + affine + final out.
__global__ __launch_bounds__(256, 2) void k_colnorm(const float2* __restrict__ F,
                                                    float* __restrict__ out,
                                                    const float* __restrict__ gamma,
                                                    const float* __restrict__ beta,
                                                    float4* __restrict__ partials) {
    const int b = blockIdx.x >> 3;          // image
    const int g = blockIdx.x & 7;           // 8 col-groups x 32 cols
    __shared__ float2 X[8 * CSTR];          // 35.1 KB
    __shared__ float2 TW[512];              // 4 KB
    __shared__ __half lvh[33 * LVSTR];      // 33.5 KB, col 32 = u=256 (g==0)
    __shared__ float4 wred[4];
    const int tid = threadIdx.x;
    {
        float sn, cs;
        __sincosf(-PI_F * (float)tid * (1.0f / 256.0f), &sn, &cs);
        TW[tid]       = make_float2(cs, sn);
        TW[tid + 256] = make_float2(-cs, -sn);
    }
    const float2* Fb = F + ((size_t)b << 18);
    float mn = 1e30f, mx = -1e30f, s1 = 0.0f, s2 = 0.0f;
    const int npass = (g == 0) ? 5 : 4;

    for (int pass = 0; pass < npass; ++pass) {
        const int u0 = (pass == 4) ? 256 : (g << 5) + (pass << 3);
        __syncthreads();                    // X free of previous-pass readers
        for (int i = tid; i < 4096; i += 256) {
            int y = i >> 3, c = i & 7;
            int u = u0 + c;
            float2 v = (u <= 256) ? Fb[(y << 9) + u] : make_float2(0.0f, 0.0f);
            X[c * CSTR + SW(drev9(y))] = v;
        }
        __syncthreads();
        {
            const int c = tid >> 5, j0 = tid & 31;
            float2* Xc = X + c * CSTR;
            #pragma unroll
            for (int t = 0; t < 8; ++t) r2bf(Xc, j0 + (t << 5));
            __builtin_amdgcn_wave_barrier();
            #pragma unroll
            for (int lg = 1; lg <= 7; lg += 2) {
                #pragma unroll
                for (int t = 0; t < 4; ++t) r4bf(Xc, TW, j0 + (t << 5), lg);
                __builtin_amdgcn_wave_barrier();
            }
        }
        __syncthreads();
        for (int i = tid; i < 4096; i += 256) {
            int y = i >> 3, c = i & 7;
            int u = u0 + c;
            if (u > 256) continue;
            float2 v = X[c * CSTR + SW(y)];
            float lv = __log2f(1.0f + sqrtf(v.x * v.x + v.y * v.y));
            int ro = (y + 256) & 511;
            int lcol = (pass == 4) ? 32 : (pass << 3) + c;
            lvh[lcol * LVSTR + ro] = __float2half(lv);
            mn = fminf(mn, lv);
            mx = fmaxf(mx, lv);
            if (u == 0 || u == 256) { s1 += lv;        s2 += lv * lv; }
            else                    { s1 += 2.0f * lv; s2 += 2.0f * lv * lv; }
        }
    }

    #pragma unroll
    for (int off = 32; off > 0; off >>= 1) {
        mn = fminf(mn, __shfl_down(mn, off, 64));
        mx = fmaxf(mx, __shfl_down(mx, off, 64));
        s1 += __shfl_down(s1, off, 64);
        s2 += __shfl_down(s2, off, 64);
    }
    const int wave = tid >> 6, lane = tid & 63;
    if (lane == 0) wred[wave] = make_float4(mn, mx, s1, s2);
    __syncthreads();
    if (tid == 0) {
        float4 r = wred[0];
        #pragma unroll
        for (int wv = 1; wv < 4; ++wv) {
            float4 q2 = wred[wv];
            r.x = fminf(r.x, q2.x);
            r.y = fmaxf(r.y, q2.y);
            r.z += q2.z;
            r.w += q2.w;
        }
        partials[blockIdx.x] = r;
    }

    cg::this_grid().sync();

    // fold this image's 8 partials into (A,B) — redundantly per thread
    float A, B;
    {
        float fmn = 1e30f, fmx = -1e30f, fs1 = 0.0f, fs2 = 0.0f;
        #pragma unroll
        for (int j = 0; j < 8; ++j) {
            float4 r = partials[(b << 3) + j];
            fmn = fminf(fmn, r.x);
            fmx = fmaxf(fmx, r.y);
            fs1 += r.z;
            fs2 += r.w;
        }
        const float N = 262144.0f;
        float mean = fs1 / N;
        float var = fmaxf(fs2 / N - mean * mean, 0.0f);
        float rng = fmx - fmn;
        float gm = gamma[0], bt = beta[0];
        if (rng > 0.0f) {
            float inv = 1.0f / rng;
            float varn = var * inv * inv;
            float sc = 1.0f / sqrtf(varn + 1e-5f);
            A = gm * sc * inv;
            B = bt - mean * A;
        } else {
            A = 0.0f;
            B = bt;
        }
    }

    // apply phase: write final out from LDS-held lv (direct + mirror)
    float* out_b = out + ((size_t)b << 18);
    for (int pass = 0; pass < npass; ++pass) {
        const int u0 = (pass == 4) ? 256 : (g << 5) + (pass << 3);
        for (int i = tid; i < 4096; i += 256) {
            int ro = i >> 3, c = i & 7;
            int u = u0 + c;
            if (u > 256) continue;
            int lcol = (pass == 4) ? 32 : (pass << 3) + c;
            float lv = __half2float(lvh[lcol * LVSTR + ro]);
            float val = A * lv + B;
            int co = (u + 256) & 511;
            out_b[(ro << 9) + co] = val;
            if (u != 0 && u != 256) {
                int rom = (512 - ro) & 511;
                out_b[(rom << 9) + (256 - u)] = val;
            }
        }
    }
}

extern "C" void kernel_launch(void* const* d_in, const int* in_sizes, int n_in,
                              void* d_out, int out_size, void* d_ws, size_t ws_size,
                              hipStream_t stream) {
    const float* x     = (const float*)d_in[0];
    const float* gamma = (const float*)d_in[1];
    const float* beta  = (const float*)d_in[2];
    float* out = (float*)d_out;

    float2* F = (float2*)d_ws;
    float4* partials = (float4*)((char*)d_ws + ((size_t)128 << 20));

    const double M00=0.65, M01=0.70, M02=0.29;
    const double M10=0.07, M11=0.99, M12=0.11;
    const double M20=0.27, M21=0.57, M22=0.78;
    const double det = M00*(M11*M22 - M12*M21)
                     - M01*(M10*M22 - M12*M20)
                     + M02*(M10*M21 - M11*M20);
    const float hw0 = (float)( (M11*M22 - M12*M21) / det);
    const float hw1 = (float)(-(M10*M22 - M12*M20) / det);
    const float hw2 = (float)( (M10*M21 - M11*M20) / det);
    const float invLA2 = (float)(log(2.0) / log(1e-6));
    const float sN = 1.0f / (512.0f * 512.0f);
    const float w0 = hw0 * invLA2 * sN;
    const float w1 = hw1 * invLA2 * sN;
    const float w2 = hw2 * invLA2 * sN;

    k_rowfft<<<64 * 64, 256, 0, stream>>>(x, F, w0, w1, w2);

    void* args[] = { (void*)&F, (void*)&out, (void*)&gamma, (void*)&beta,
                     (void*)&partials };
    hipLaunchCooperativeKernel((const void*)k_colnorm, dim3(512), dim3(256),
                               args, 0, stream);
}

// Round 5
// 130.100 us; speedup vs baseline: 1.5309x; 1.5309x over previous
//
#include <hip/hip_runtime.h>
#include <hip/hip_fp16.h>
#include <math.h>

// ---------------------------------------------------------------------------
// HematoxylinFFTModel round 5: back to 4-kernel structure (round-4 coop fusion
// regressed: 2 blocks/CU residency killed latency hiding). Cut traffic:
//  - F intermediate in fp16 (half2), compact row stride 264 (34 MB vs 67).
//  - logmag as u16 fixed point, HALF-PLANE only (u=0..256, 16.5 MB); k_norm
//    reconstructs the Hermitian mirror and writes out exactly once (no rmw).
// Total HBM ~366 MB vs ~590 MB in round 3.
// ---------------------------------------------------------------------------

#define PI_F 3.14159265358979323846f
#define SW(i) ((i) + ((i) >> 4))
#define FSTR 544            // rowfft per-FFT LDS stride in float2
#define CSTR 548            // colfft per-column LDS stride
#define FROW 264            // F row stride in half2 (cols 0..256 live)
#define LMSTR 264           // logmag row stride in u16 (cols 0..256 live)
#define LVMAX 1.6f          // provable bound: lv = log2(1+mag) <= log2(2.9)
#define QE (65535.0f / LVMAX)
#define QD (LVMAX / 65535.0f)

// digit reversal for stage order [2,4,4,4,4]
__device__ __forceinline__ int drev9(int n) {
    return ((n & 3) << 7) | (((n >> 2) & 3) << 5) | (((n >> 4) & 3) << 3)
         | (((n >> 6) & 3) << 1) | (n >> 8);
}

__device__ __forceinline__ float2 cmul(float2 a, float2 w) {
    return make_float2(a.x * w.x - a.y * w.y, a.x * w.y + a.y * w.x);
}

__device__ __forceinline__ void r2bf(float2* Xc, int m) {
    float2 a = Xc[SW(2 * m)], b = Xc[SW(2 * m + 1)];
    Xc[SW(2 * m)]     = make_float2(a.x + b.x, a.y + b.y);
    Xc[SW(2 * m + 1)] = make_float2(a.x - b.x, a.y - b.y);
}

__device__ __forceinline__ void r4bf(float2* Xc, const float2* TW, int j, int log2L) {
    const int L = 1 << log2L;
    const int kk = j & (L - 1);
    const int base = ((j >> log2L) << (log2L + 2)) + kk;
    const int t1 = kk << (7 - log2L);
    float2 a0 = Xc[SW(base)];
    float2 a1 = cmul(Xc[SW(base + L)],     TW[t1]);
    float2 a2 = cmul(Xc[SW(base + 2 * L)], TW[2 * t1]);
    float2 a3 = cmul(Xc[SW(base + 3 * L)], TW[3 * t1]);
    float2 t0 = make_float2(a0.x + a2.x, a0.y + a2.y);
    float2 u0 = make_float2(a0.x - a2.x, a0.y - a2.y);
    float2 t2 = make_float2(a1.x + a3.x, a1.y + a3.y);
    float2 u1 = make_float2(a1.x - a3.x, a1.y - a3.y);
    Xc[SW(base)]         = make_float2(t0.x + t2.x, t0.y + t2.y);
    Xc[SW(base + 2 * L)] = make_float2(t0.x - t2.x, t0.y - t2.y);
    Xc[SW(base + L)]     = make_float2(u0.x + u1.y, u0.y - u1.x);
    Xc[SW(base + 3 * L)] = make_float2(u0.x - u1.y, u0.y + u1.x);
}

__device__ __forceinline__ void hstore(float2* Xw, int c,
                                       float r0v, float g0v, float b0v,
                                       float r1v, float g1v, float b1v,
                                       float w0, float w1, float w2) {
    r0v = fminf(fmaxf(r0v, 1e-6f), 1.0f);
    g0v = fminf(fmaxf(g0v, 1e-6f), 1.0f);
    b0v = fminf(fmaxf(b0v, 1e-6f), 1.0f);
    r1v = fminf(fmaxf(r1v, 1e-6f), 1.0f);
    g1v = fminf(fmaxf(g1v, 1e-6f), 1.0f);
    b1v = fminf(fmaxf(b1v, 1e-6f), 1.0f);
    float h0 = fmaxf(w0 * __log2f(r0v) + w1 * __log2f(g0v) + w2 * __log2f(b0v), 0.0f);
    float h1 = fmaxf(w0 * __log2f(r1v) + w1 * __log2f(g1v) + w2 * __log2f(b1v), 0.0f);
    Xw[SW(drev9(c))] = make_float2(h0, h1);
}

// Pass 1: hematoxylin + packed row-pair FFT, 4 FFTs (8 rows) per block,
// Hermitian unpack, fp16 store of cols 0..256.
__global__ __launch_bounds__(256) void k_rowfft(const float* __restrict__ x,
                                                __half2* __restrict__ Fh,
                                                float w0, float w1, float w2) {
    const int b = blockIdx.x >> 6;
    const int p = blockIdx.x & 63;
    __shared__ float2 X[4 * FSTR];
    __shared__ float2 TW[512];
    const int tid = threadIdx.x;
    {
        float sn, cs;
        __sincosf(-PI_F * (float)tid * (1.0f / 256.0f), &sn, &cs);
        TW[tid]       = make_float2(cs, sn);
        TW[tid + 256] = make_float2(-cs, -sn);
    }
    const int w = tid >> 6, lane = tid & 63;
    float2* Xw = X + w * FSTR;
    const float* xb = x + (size_t)b * 786432;
    const int r0 = (p << 3) + (w << 1);

    #pragma unroll
    for (int q = 0; q < 2; ++q) {
        const int cb = (q << 8) + (lane << 2);
        float4 R0 = *(const float4*)(xb +          (r0 << 9) + cb);
        float4 G0 = *(const float4*)(xb + 262144 + (r0 << 9) + cb);
        float4 B0 = *(const float4*)(xb + 524288 + (r0 << 9) + cb);
        float4 R1 = *(const float4*)(xb +          ((r0 + 1) << 9) + cb);
        float4 G1 = *(const float4*)(xb + 262144 + ((r0 + 1) << 9) + cb);
        float4 B1 = *(const float4*)(xb + 524288 + ((r0 + 1) << 9) + cb);
        hstore(Xw, cb + 0, R0.x, G0.x, B0.x, R1.x, G1.x, B1.x, w0, w1, w2);
        hstore(Xw, cb + 1, R0.y, G0.y, B0.y, R1.y, G1.y, B1.y, w0, w1, w2);
        hstore(Xw, cb + 2, R0.z, G0.z, B0.z, R1.z, G1.z, B1.z, w0, w1, w2);
        hstore(Xw, cb + 3, R0.w, G0.w, B0.w, R1.w, G1.w, B1.w, w0, w1, w2);
    }
    __syncthreads();

    #pragma unroll
    for (int t = 0; t < 4; ++t) r2bf(Xw, lane + (t << 6));
    __builtin_amdgcn_wave_barrier();
    #pragma unroll
    for (int lg = 1; lg <= 7; lg += 2) {
        r4bf(Xw, TW, lane, lg);
        r4bf(Xw, TW, lane + 64, lg);
        __builtin_amdgcn_wave_barrier();
    }

    __half2* Fb = Fh + (size_t)b * (512 * FROW);
    #pragma unroll
    for (int t = 0; t < 4; ++t) {
        int k = lane + (t << 6);
        int m = (512 - k) & 511;
        float2 zk = Xw[SW(k)];
        float2 zm = Xw[SW(m)];
        Fb[r0 * FROW + k]       = __floats2half2_rn(0.5f * (zk.x + zm.x),  0.5f * (zk.y - zm.y));
        Fb[(r0 + 1) * FROW + k] = __floats2half2_rn(0.5f * (zk.y + zm.y), -0.5f * (zk.x - zm.x));
    }
    if (lane == 0) {
        float2 z = Xw[SW(256)];
        Fb[r0 * FROW + 256]       = __floats2half2_rn(z.x, 0.0f);
        Fb[(r0 + 1) * FROW + 256] = __floats2half2_rn(z.y, 0.0f);
    }
}

// Pass 2: column FFTs for u=0..256 (17 groups x 16 cols), u16 half-plane
// logmag store (rows pre-fftshifted), stats partials (mirror counted 2x).
__global__ __launch_bounds__(256) void k_colfft(const __half2* __restrict__ Fh,
                                                unsigned short* __restrict__ lmu,
                                                float4* __restrict__ partials) {
    const int b = blockIdx.x / 17;
    const int g = blockIdx.x % 17;
    __shared__ float2 X[8 * CSTR];
    __shared__ float2 TW[512];
    __shared__ float4 wred[4];
    const int tid = threadIdx.x;
    {
        float sn, cs;
        __sincosf(-PI_F * (float)tid * (1.0f / 256.0f), &sn, &cs);
        TW[tid]       = make_float2(cs, sn);
        TW[tid + 256] = make_float2(-cs, -sn);
    }
    const __half2* Fb = Fh + (size_t)b * (512 * FROW);
    unsigned short* lm_b = lmu + (size_t)b * (512 * LMSTR);
    float mn = 1e30f, mx = -1e30f, s1 = 0.0f, s2 = 0.0f;

    for (int pass = 0; pass < 2; ++pass) {
        const int u0 = (g << 4) + (pass << 3);
        __syncthreads();
        for (int i = tid; i < 4096; i += 256) {
            int y = i >> 3, c = i & 7;
            int u = u0 + c;
            float2 v = (u <= 256) ? __half22float2(Fb[y * FROW + u])
                                  : make_float2(0.0f, 0.0f);
            X[c * CSTR + SW(drev9(y))] = v;
        }
        __syncthreads();
        {
            const int c = tid >> 5, j0 = tid & 31;
            float2* Xc = X + c * CSTR;
            #pragma unroll
            for (int t = 0; t < 8; ++t) r2bf(Xc, j0 + (t << 5));
            __builtin_amdgcn_wave_barrier();
            #pragma unroll
            for (int lg = 1; lg <= 7; lg += 2) {
                #pragma unroll
                for (int t = 0; t < 4; ++t) r4bf(Xc, TW, j0 + (t << 5), lg);
                __builtin_amdgcn_wave_barrier();
            }
        }
        __syncthreads();
        for (int i = tid; i < 4096; i += 256) {
            int y = i >> 3, c = i & 7;
            int u = u0 + c;
            if (u > 256) continue;
            float2 v = X[c * CSTR + SW(y)];
            float lv = __log2f(1.0f + sqrtf(v.x * v.x + v.y * v.y));
            int ro = (y + 256) & 511;
            unsigned q = (unsigned)__float2uint_rn(fminf(lv, LVMAX) * QE);
            lm_b[ro * LMSTR + u] = (unsigned short)q;
            mn = fminf(mn, lv);
            mx = fmaxf(mx, lv);
            if (u == 0 || u == 256) { s1 += lv;        s2 += lv * lv; }
            else                    { s1 += 2.0f * lv; s2 += 2.0f * lv * lv; }
        }
    }

    #pragma unroll
    for (int off = 32; off > 0; off >>= 1) {
        mn = fminf(mn, __shfl_down(mn, off, 64));
        mx = fmaxf(mx, __shfl_down(mx, off, 64));
        s1 += __shfl_down(s1, off, 64);
        s2 += __shfl_down(s2, off, 64);
    }
    const int wave = tid >> 6, lane = tid & 63;
    if (lane == 0) wred[wave] = make_float4(mn, mx, s1, s2);
    __syncthreads();
    if (tid == 0) {
        float4 r = wred[0];
        #pragma unroll
        for (int wv = 1; wv < 4; ++wv) {
            float4 q2 = wred[wv];
            r.x = fminf(r.x, q2.x);
            r.y = fmaxf(r.y, q2.y);
            r.z += q2.z;
            r.w += q2.w;
        }
        partials[blockIdx.x] = r;
    }
}

// Pass 3: fold 17 partials/image into per-image affine (A,B).
__global__ __launch_bounds__(64) void k_coeff(const float4* __restrict__ partials,
                                              const float* __restrict__ gamma,
                                              const float* __restrict__ beta,
                                              float2* __restrict__ coeff) {
    const int b = blockIdx.x;
    float mn = 1e30f, mx = -1e30f, s1 = 0.0f, s2 = 0.0f;
    if (threadIdx.x < 17) {
        float4 r = partials[b * 17 + threadIdx.x];
        mn = r.x; mx = r.y; s1 = r.z; s2 = r.w;
    }
    #pragma unroll
    for (int off = 32; off > 0; off >>= 1) {
        mn = fminf(mn, __shfl_down(mn, off, 64));
        mx = fmaxf(mx, __shfl_down(mx, off, 64));
        s1 += __shfl_down(s1, off, 64);
        s2 += __shfl_down(s2, off, 64);
    }
    if (threadIdx.x == 0) {
        const float N = 262144.0f;
        float mean = s1 / N;
        float var = fmaxf(s2 / N - mean * mean, 0.0f);
        float rng = mx - mn;
        float g = gamma[0], bt = beta[0];
        float A, B;
        if (rng > 0.0f) {
            float inv = 1.0f / rng;
            float varn = var * inv * inv;
            float sc = 1.0f / sqrtf(varn + 1e-5f);
            A = g * sc * inv;
            B = bt - mean * A;
        } else {
            A = 0.0f;
            B = bt;
        }
        coeff[b] = make_float2(A, B);
    }
}

// Pass 4: out = A*lv + B, reconstructing Hermitian mirror from half-plane lmu.
// Block p handles output rows {p, 512-p} (p=0 -> {0, 256}); each row needs
// lmu row r (direct, co>=256 and co=0) and lmu row (512-r)&511 (mirror,
// co=1..255 via u'=256-co).
__global__ __launch_bounds__(256) void k_norm(const unsigned short* __restrict__ lmu,
                                              float* __restrict__ out,
                                              const float2* __restrict__ coeff) {
    const int p = blockIdx.x & 255;
    const int b = blockIdx.x >> 8;
    const float2 ab = coeff[b];
    const float A = ab.x, B = ab.y;
    const int rA = p;
    const int rB = (p == 0) ? 256 : 512 - p;
    const unsigned short* lb = lmu + (size_t)b * (512 * LMSTR);
    float* ob = out + ((size_t)b << 18);
    const int tid = threadIdx.x;
    #pragma unroll
    for (int hh = 0; hh < 2; ++hh) {
        const int r = hh ? rB : rA;
        const int rm = (512 - r) & 511;
        const unsigned short* Ld = lb + (size_t)r * LMSTR;
        const unsigned short* Lm = lb + (size_t)rm * LMSTR;
        // co = tid + 256  ->  u = tid (direct)
        float lvd = (float)Ld[tid] * QD;
        ob[(r << 9) + 256 + tid] = A * lvd + B;
        // co = tid (0..255): tid==0 -> u=256 direct; else mirror u'=256-tid
        float lvm = (tid == 0) ? ((float)Ld[256] * QD)
                               : ((float)Lm[256 - tid] * QD);
        ob[(r << 9) + tid] = A * lvm + B;
    }
}

extern "C" void kernel_launch(void* const* d_in, const int* in_sizes, int n_in,
                              void* d_out, int out_size, void* d_ws, size_t ws_size,
                              hipStream_t stream) {
    const float* x     = (const float*)d_in[0];
    const float* gamma = (const float*)d_in[1];
    const float* beta  = (const float*)d_in[2];
    float* out = (float*)d_out;

    // ws layout: Fh (64 img x 512 x 264 half2 = 34.6 MB) | lmu (17.3 MB) |
    //            partials | coeff
    __half2* Fh = (__half2*)d_ws;
    unsigned short* lmu = (unsigned short*)((char*)d_ws + ((size_t)40 << 20));
    float4* partials = (float4*)((char*)d_ws + ((size_t)60 << 20));
    float2* coeff    = (float2*)((char*)d_ws + ((size_t)60 << 20) + 64 * 17 * sizeof(float4));

    const double M00=0.65, M01=0.70, M02=0.29;
    const double M10=0.07, M11=0.99, M12=0.11;
    const double M20=0.27, M21=0.57, M22=0.78;
    const double det = M00*(M11*M22 - M12*M21)
                     - M01*(M10*M22 - M12*M20)
                     + M02*(M10*M21 - M11*M20);
    const float hw0 = (float)( (M11*M22 - M12*M21) / det);
    const float hw1 = (float)(-(M10*M22 - M12*M20) / det);
    const float hw2 = (float)( (M10*M21 - M11*M20) / det);
    const float invLA2 = (float)(log(2.0) / log(1e-6));
    const float sN = 1.0f / (512.0f * 512.0f);
    const float w0 = hw0 * invLA2 * sN;
    const float w1 = hw1 * invLA2 * sN;
    const float w2 = hw2 * invLA2 * sN;

    k_rowfft<<<64 * 64, 256, 0, stream>>>(x, Fh, w0, w1, w2);
    k_colfft<<<64 * 17, 256, 0, stream>>>(Fh, lmu, partials);
    k_coeff<<<64, 64, 0, stream>>>(partials, gamma, beta, coeff);
    k_norm<<<64 * 256, 256, 0, stream>>>(lmu, out, coeff);
}

// Round 6
// 123.103 us; speedup vs baseline: 1.6179x; 1.0568x over previous
//
#include <hip/hip_runtime.h>
#include <hip/hip_fp16.h>
#include <math.h>

// ---------------------------------------------------------------------------
// HematoxylinFFTModel round 6: register-blocked radix-8 FFT (512 = 8^3).
//  - DIF, natural-order input (no bit-reversal staging), 3 LDS round trips
//    (48 b64 ops/lane vs 80 for radix-2+4), 2 wave_barriers per FFT.
//  - output lands octal-digit-reversed; unpack/magnitude index via odrev(k).
//  - LDS map MU(p)=72*(p>>6)+(p&56)+((p&7)^((p>>3)&7)): <=4-way conflicts in
//    every phase (stride-64, stride-8, contiguous-8 all spread).
//  - rowfft: zero __syncthreads (per-wave redundant TW fill, wave-local FFT).
//  - colfft: 512-thread blocks, 1 wave per column, 2 syncthreads per pass.
//  - k_coeff folded into k_norm (uniform scalar loads of 17 partials).
// ---------------------------------------------------------------------------

#define PI_F 3.14159265358979323846f
#define FROW 264            // F row stride in half2 (cols 0..256 live)
#define LMSTR 264           // logmag row stride in u16 (cols 0..256 live)
#define LVMAX 1.6f          // bound: lv = log2(1+mag) <= log2(2.9) < 1.6
#define QE (65535.0f / LVMAX)
#define QD (LVMAX / 65535.0f)
#define XSTR 568            // per-FFT LDS stride in float2 (MU(511)+8)

__device__ __forceinline__ int MU(int p) {
    return ((p >> 6) * 72) + (p & 56) + ((p & 7) ^ ((p >> 3) & 7));
}
// octal digit reversal: k = k2*64 + k1*8 + k0 -> k0*64 + k1*8 + k2
__device__ __forceinline__ int odrev(int k) {
    return ((k & 7) << 6) | (k & 56) | (k >> 6);
}

__device__ __forceinline__ float2 cadd(float2 a, float2 b) { return make_float2(a.x + b.x, a.y + b.y); }
__device__ __forceinline__ float2 csub(float2 a, float2 b) { return make_float2(a.x - b.x, a.y - b.y); }
__device__ __forceinline__ float2 cmul(float2 a, float2 w) {
    return make_float2(a.x * w.x - a.y * w.y, a.x * w.y + a.y * w.x);
}

// 8-point DFT, natural-in / natural-out (DIF inside), w8 = e^{-2pi i/8}
__device__ __forceinline__ void dft8(float2 v[8]) {
    const float s = 0.70710678118654752f;
    float2 a0 = cadd(v[0], v[4]), b0 = csub(v[0], v[4]);
    float2 a1 = cadd(v[1], v[5]), b1 = csub(v[1], v[5]);
    float2 a2 = cadd(v[2], v[6]), b2 = csub(v[2], v[6]);
    float2 a3 = cadd(v[3], v[7]), b3 = csub(v[3], v[7]);
    b1 = make_float2(s * (b1.x + b1.y), s * (b1.y - b1.x));    // *w8^1
    b2 = make_float2(b2.y, -b2.x);                              // *w8^2 = -i
    b3 = make_float2(s * (b3.y - b3.x), -s * (b3.x + b3.y));    // *w8^3
    float2 c0 = cadd(a0, a2), c1 = cadd(a1, a3);
    float2 d0 = csub(a0, a2), d1 = csub(a1, a3);
    d1 = make_float2(d1.y, -d1.x);
    v[0] = cadd(c0, c1); v[4] = csub(c0, c1);
    v[2] = cadd(d0, d1); v[6] = csub(d0, d1);
    float2 e0 = cadd(b0, b2), e1 = cadd(b1, b3);
    float2 f0 = csub(b0, b2), f1 = csub(b1, b3);
    f1 = make_float2(f1.y, -f1.x);
    v[1] = cadd(e0, e1); v[5] = csub(e0, e1);
    v[3] = cadd(f0, f1); v[7] = csub(f0, f1);
}

// 512-pt wave-synchronous FFT, natural input in Xw[MU(.)], output
// stored[MU(p)] = Z[odrev(p)]. 3 phases, trailing wave_barrier included.
__device__ __forceinline__ void fft512_reg(float2* Xw, const float2* TW, int lane) {
    float2 v[8];
    // P1: gather stride-64, dft8 over blocks, twiddle W^{lane*m}, in-place
    #pragma unroll
    for (int m = 0; m < 8; ++m) v[m] = Xw[MU(lane + (m << 6))];
    dft8(v);
    #pragma unroll
    for (int m = 1; m < 8; ++m) v[m] = cmul(v[m], TW[(lane * m) & 511]);
    #pragma unroll
    for (int m = 0; m < 8; ++m) Xw[MU((m << 6) + lane)] = v[m];
    __builtin_amdgcn_wave_barrier();
    // P2: within block b, gather stride-8 at offset t, twiddle W64^{t*m}
    const int b = lane >> 3, t = lane & 7;
    const int base2 = (b << 6) + t;
    #pragma unroll
    for (int m = 0; m < 8; ++m) v[m] = Xw[MU(base2 + (m << 3))];
    dft8(v);
    #pragma unroll
    for (int m = 1; m < 8; ++m) v[m] = cmul(v[m], TW[(t * m) << 3]);
    #pragma unroll
    for (int m = 0; m < 8; ++m) Xw[MU(base2 + (m << 3))] = v[m];
    __builtin_amdgcn_wave_barrier();
    // P3: contiguous-8 (b = lane>>3, m' = lane&7), no twiddle, in-place
    const int base3 = (b << 6) + (t << 3);
    #pragma unroll
    for (int j = 0; j < 8; ++j) v[j] = Xw[MU(base3 + j)];
    dft8(v);
    #pragma unroll
    for (int sidx = 0; sidx < 8; ++sidx) Xw[MU(base3 + sidx)] = v[sidx];
    __builtin_amdgcn_wave_barrier();
}

__device__ __forceinline__ void hstore(float2* Xw, int c,
                                       float r0v, float g0v, float b0v,
                                       float r1v, float g1v, float b1v,
                                       float w0, float w1, float w2) {
    r0v = fminf(fmaxf(r0v, 1e-6f), 1.0f);
    g0v = fminf(fmaxf(g0v, 1e-6f), 1.0f);
    b0v = fminf(fmaxf(b0v, 1e-6f), 1.0f);
    r1v = fminf(fmaxf(r1v, 1e-6f), 1.0f);
    g1v = fminf(fmaxf(g1v, 1e-6f), 1.0f);
    b1v = fminf(fmaxf(b1v, 1e-6f), 1.0f);
    float h0 = fmaxf(w0 * __log2f(r0v) + w1 * __log2f(g0v) + w2 * __log2f(b0v), 0.0f);
    float h1 = fmaxf(w0 * __log2f(r1v) + w1 * __log2f(g1v) + w2 * __log2f(b1v), 0.0f);
    Xw[MU(c)] = make_float2(h0, h1);     // natural order (DIF input)
}

// Pass 1: hematoxylin + packed row-pair FFT, 4 waves = 4 FFTs (8 rows)/block,
// Hermitian unpack via odrev, fp16 store of cols 0..256. No __syncthreads.
__global__ __launch_bounds__(256) void k_rowfft(const float* __restrict__ x,
                                                __half2* __restrict__ Fh,
                                                float w0, float w1, float w2) {
    const int b = blockIdx.x >> 6;
    const int p = blockIdx.x & 63;
    __shared__ float2 X[4 * XSTR];
    __shared__ float2 TW[512];
    const int tid = threadIdx.x;
    const int w = tid >> 6, lane = tid & 63;
    // per-wave redundant TW fill (benign same-value race across waves)
    #pragma unroll
    for (int t = 0; t < 8; ++t) {
        int idx = lane + (t << 6);
        float sn, cs;
        __sincosf(-PI_F * (float)idx * (1.0f / 256.0f), &sn, &cs);
        TW[idx] = make_float2(cs, sn);
    }
    float2* Xw = X + w * XSTR;
    const float* xb = x + (size_t)b * 786432;
    const int r0 = (p << 3) + (w << 1);

    #pragma unroll
    for (int q = 0; q < 2; ++q) {
        const int cb = (q << 8) + (lane << 2);
        float4 R0 = *(const float4*)(xb +          (r0 << 9) + cb);
        float4 G0 = *(const float4*)(xb + 262144 + (r0 << 9) + cb);
        float4 B0 = *(const float4*)(xb + 524288 + (r0 << 9) + cb);
        float4 R1 = *(const float4*)(xb +          ((r0 + 1) << 9) + cb);
        float4 G1 = *(const float4*)(xb + 262144 + ((r0 + 1) << 9) + cb);
        float4 B1 = *(const float4*)(xb + 524288 + ((r0 + 1) << 9) + cb);
        hstore(Xw, cb + 0, R0.x, G0.x, B0.x, R1.x, G1.x, B1.x, w0, w1, w2);
        hstore(Xw, cb + 1, R0.y, G0.y, B0.y, R1.y, G1.y, B1.y, w0, w1, w2);
        hstore(Xw, cb + 2, R0.z, G0.z, B0.z, R1.z, G1.z, B1.z, w0, w1, w2);
        hstore(Xw, cb + 3, R0.w, G0.w, B0.w, R1.w, G1.w, B1.w, w0, w1, w2);
    }
    __builtin_amdgcn_wave_barrier();

    fft512_reg(Xw, TW, lane);

    // Hermitian unpack: Z[k] = stored[MU(odrev(k))]
    __half2* Fb = Fh + (size_t)b * (512 * FROW);
    #pragma unroll
    for (int t = 0; t < 4; ++t) {
        int k = lane + (t << 6);
        int m = (512 - k) & 511;
        float2 zk = Xw[MU(odrev(k))];
        float2 zm = Xw[MU(odrev(m))];
        Fb[r0 * FROW + k]       = __floats2half2_rn(0.5f * (zk.x + zm.x),  0.5f * (zk.y - zm.y));
        Fb[(r0 + 1) * FROW + k] = __floats2half2_rn(0.5f * (zk.y + zm.y), -0.5f * (zk.x - zm.x));
    }
    if (lane == 0) {
        float2 z = Xw[MU(odrev(256))];
        Fb[r0 * FROW + 256]       = __floats2half2_rn(z.x, 0.0f);
        Fb[(r0 + 1) * FROW + 256] = __floats2half2_rn(z.y, 0.0f);
    }
}

// Pass 2: 512 threads, 8 waves; per pass 8 columns (1/wave); 2 passes = 16
// cols/block, 17 groups. Magnitude via odrev, u16 half-plane store, stats.
__global__ __launch_bounds__(512) void k_colfft(const __half2* __restrict__ Fh,
                                                unsigned short* __restrict__ lmu,
                                                float4* __restrict__ partials) {
    const int b = blockIdx.x / 17;
    const int g = blockIdx.x % 17;
    __shared__ float2 X[8 * XSTR];      // 36.4 KB
    __shared__ float2 TW[512];
    __shared__ float4 wred[8];
    const int tid = threadIdx.x;
    const int w = tid >> 6, lane = tid & 63;
    {
        float sn, cs;
        __sincosf(-PI_F * (float)tid * (1.0f / 256.0f), &sn, &cs);
        TW[tid] = make_float2(cs, sn);  // tid 0..511 covers all
    }
    const __half2* Fb = Fh + (size_t)b * (512 * FROW);
    unsigned short* lm_b = lmu + (size_t)b * (512 * LMSTR);
    float mn = 1e30f, mx = -1e30f, s1 = 0.0f, s2 = 0.0f;

    for (int pass = 0; pass < 2; ++pass) {
        const int u0 = (g << 4) + (pass << 3);
        __syncthreads();                // prev-pass readers done; TW ready
        for (int i = tid; i < 4096; i += 512) {
            int y = i >> 3, c = i & 7;
            int u = u0 + c;
            float2 v = (u <= 256) ? __half22float2(Fb[y * FROW + u])
                                  : make_float2(0.0f, 0.0f);
            X[c * XSTR + MU(y)] = v;    // natural order
        }
        __syncthreads();
        fft512_reg(X + w * XSTR, TW, lane);   // wave w's column
        __syncthreads();
        for (int i = tid; i < 4096; i += 512) {
            int k = i >> 3, c = i & 7;
            int u = u0 + c;
            if (u > 256) continue;
            float2 v = X[c * XSTR + MU(odrev(k))];
            float lv = __log2f(1.0f + sqrtf(v.x * v.x + v.y * v.y));
            int ro = (k + 256) & 511;
            unsigned q = (unsigned)__float2uint_rn(fminf(lv, LVMAX) * QE);
            lm_b[ro * LMSTR + u] = (unsigned short)q;
            mn = fminf(mn, lv);
            mx = fmaxf(mx, lv);
            if (u == 0 || u == 256) { s1 += lv;        s2 += lv * lv; }
            else                    { s1 += 2.0f * lv; s2 += 2.0f * lv * lv; }
        }
    }

    #pragma unroll
    for (int off = 32; off > 0; off >>= 1) {
        mn = fminf(mn, __shfl_down(mn, off, 64));
        mx = fmaxf(mx, __shfl_down(mx, off, 64));
        s1 += __shfl_down(s1, off, 64);
        s2 += __shfl_down(s2, off, 64);
    }
    if (lane == 0) wred[w] = make_float4(mn, mx, s1, s2);
    __syncthreads();
    if (tid == 0) {
        float4 r = wred[0];
        #pragma unroll
        for (int wv = 1; wv < 8; ++wv) {
            float4 q2 = wred[wv];
            r.x = fminf(r.x, q2.x);
            r.y = fmaxf(r.y, q2.y);
            r.z += q2.z;
            r.w += q2.w;
        }
        partials[blockIdx.x] = r;
    }
}

// Pass 3: out = A*lv + B with (A,B) folded per-block from 17 partials
// (uniform scalar loads), Hermitian mirror reconstruction from half-plane.
__global__ __launch_bounds__(256) void k_norm(const unsigned short* __restrict__ lmu,
                                              float* __restrict__ out,
                                              const float4* __restrict__ partials,
                                              const float* __restrict__ gamma,
                                              const float* __restrict__ beta) {
    const int p = blockIdx.x & 255;
    const int b = blockIdx.x >> 8;
    float A, B;
    {
        float mn = 1e30f, mx = -1e30f, s1 = 0.0f, s2 = 0.0f;
        #pragma unroll 1
        for (int j = 0; j < 17; ++j) {
            float4 r = partials[b * 17 + j];
            mn = fminf(mn, r.x);
            mx = fmaxf(mx, r.y);
            s1 += r.z;
            s2 += r.w;
        }
        const float N = 262144.0f;
        float mean = s1 / N;
        float var = fmaxf(s2 / N - mean * mean, 0.0f);
        float rng = mx - mn;
        float gm = gamma[0], bt = beta[0];
        if (rng > 0.0f) {
            float inv = 1.0f / rng;
            float varn = var * inv * inv;
            float sc = 1.0f / sqrtf(varn + 1e-5f);
            A = gm * sc * inv;
            B = bt - mean * A;
        } else {
            A = 0.0f;
            B = bt;
        }
    }
    const int rA = p;
    const int rB = (p == 0) ? 256 : 512 - p;
    const unsigned short* lb = lmu + (size_t)b * (512 * LMSTR);
    float* ob = out + ((size_t)b << 18);
    const int tid = threadIdx.x;
    #pragma unroll
    for (int hh = 0; hh < 2; ++hh) {
        const int r = hh ? rB : rA;
        const int rm = (512 - r) & 511;
        const unsigned short* Ld = lb + (size_t)r * LMSTR;
        const unsigned short* Lm = lb + (size_t)rm * LMSTR;
        float lvd = (float)Ld[tid] * QD;
        ob[(r << 9) + 256 + tid] = A * lvd + B;
        float lvm = (tid == 0) ? ((float)Ld[256] * QD)
                               : ((float)Lm[256 - tid] * QD);
        ob[(r << 9) + tid] = A * lvm + B;
    }
}

extern "C" void kernel_launch(void* const* d_in, const int* in_sizes, int n_in,
                              void* d_out, int out_size, void* d_ws, size_t ws_size,
                              hipStream_t stream) {
    const float* x     = (const float*)d_in[0];
    const float* gamma = (const float*)d_in[1];
    const float* beta  = (const float*)d_in[2];
    float* out = (float*)d_out;

    // ws: Fh (34.6 MB) | lmu (17.3 MB @40MB) | partials (@60MB)
    __half2* Fh = (__half2*)d_ws;
    unsigned short* lmu = (unsigned short*)((char*)d_ws + ((size_t)40 << 20));
    float4* partials = (float4*)((char*)d_ws + ((size_t)60 << 20));

    const double M00=0.65, M01=0.70, M02=0.29;
    const double M10=0.07, M11=0.99, M12=0.11;
    const double M20=0.27, M21=0.57, M22=0.78;
    const double det = M00*(M11*M22 - M12*M21)
                     - M01*(M10*M22 - M12*M20)
                     + M02*(M10*M21 - M11*M20);
    const float hw0 = (float)( (M11*M22 - M12*M21) / det);
    const float hw1 = (float)(-(M10*M22 - M12*M20) / det);
    const float hw2 = (float)( (M10*M21 - M11*M20) / det);
    const float invLA2 = (float)(log(2.0) / log(1e-6));
    const float sN = 1.0f / (512.0f * 512.0f);
    const float w0 = hw0 * invLA2 * sN;
    const float w1 = hw1 * invLA2 * sN;
    const float w2 = hw2 * invLA2 * sN;

    k_rowfft<<<64 * 64, 256, 0, stream>>>(x, Fh, w0, w1, w2);
    k_colfft<<<64 * 17, 512, 0, stream>>>(Fh, lmu, partials);
    k_norm<<<64 * 256, 256, 0, stream>>>(lmu, out, partials, gamma, beta);
}